// Round 5
// baseline (406.039 us; speedup 1.0000x reference)
//
#include <hip/hip_runtime.h>
#include <stdint.h>

#define K_DIM 4096
#define N_DIM 4096
#define M_DIM 8192   // B*S = 4*2048
#define S_ROWS 2048
#define NT 32        // K tiles of 128 bytes

typedef int v4i __attribute__((ext_vector_type(4)));

__device__ __forceinline__ void gload16(const void* g, void* l) {
    __builtin_amdgcn_global_load_lds(
        (const __attribute__((address_space(1))) unsigned int*)g,
        (__attribute__((address_space(3))) unsigned int*)l, 16, 0, 0);
}

__device__ __forceinline__ void barrier() {
    asm volatile("" ::: "memory");
    __builtin_amdgcn_s_barrier();
    asm volatile("" ::: "memory");
}

// ---------------- 1. fused prep: absmax (blocks 0..4095) + wtrans (4096..8191) ----------------
__global__ void prep1_kernel(const float* __restrict__ x, unsigned* __restrict__ amax,
                             const int* __restrict__ wq, char* __restrict__ wt) {
    __shared__ unsigned lds[64 * 17];
    if (blockIdx.x < 4096) {
        int b = blockIdx.x >> 10;
        int bx = blockIdx.x & 1023;
        const float4* xb = (const float4*)(x + (size_t)b * S_ROWS * K_DIM);
        int tid = bx * 256 + threadIdx.x;
        const int stride = 1024 * 256;
        float m = 0.f;
#pragma unroll
        for (int i = 0; i < 8; ++i) {
            float4 v = xb[tid + i * stride];
            m = fmaxf(m, fmaxf(fmaxf(fabsf(v.x), fabsf(v.y)),
                               fmaxf(fabsf(v.z), fabsf(v.w))));
        }
#pragma unroll
        for (int off = 32; off; off >>= 1)
            m = fmaxf(m, __shfl_xor(m, off));
        float* red = (float*)lds;
        if ((threadIdx.x & 63) == 0) red[threadIdx.x >> 6] = m;
        __syncthreads();
        if (threadIdx.x == 0) {
            m = fmaxf(fmaxf(red[0], red[1]), fmaxf(red[2], red[3]));
            atomicMax(&amax[b], __float_as_uint(m));
        }
    } else {
        int wb = blockIdx.x - 4096;
        int n0 = (wb & 63) * 64;
        int k0 = (wb >> 6) * 64;
        int t = threadIdx.x;
        int c = t & 63;
        int g = t >> 6;
#pragma unroll
        for (int rep = 0; rep < 4; ++rep) {
            int kb = g * 16 + rep * 4;
            int v0 = wq[(size_t)(k0 + kb + 0) * N_DIM + n0 + c];
            int v1 = wq[(size_t)(k0 + kb + 1) * N_DIM + n0 + c];
            int v2 = wq[(size_t)(k0 + kb + 2) * N_DIM + n0 + c];
            int v3 = wq[(size_t)(k0 + kb + 3) * N_DIM + n0 + c];
            lds[c * 17 + (kb >> 2)] =
                (v0 & 255) | ((v1 & 255) << 8) | ((v2 & 255) << 16) | ((v3 & 255) << 24);
        }
        __syncthreads();
        int row = t >> 2;
        int ch = t & 3;
        uint4 o;
        o.x = lds[row * 17 + ch * 4 + 0];
        o.y = lds[row * 17 + ch * 4 + 1];
        o.z = lds[row * 17 + ch * 4 + 2];
        o.w = lds[row * 17 + ch * 4 + 3];
        *(uint4*)(wt + (size_t)(n0 + row) * K_DIM + k0 + ch * 16) = o;
    }
}

// ---------------- 2. quantize x -> int8 ----------------
__global__ void quant_kernel(const float* __restrict__ x,
                             const unsigned* __restrict__ amax,
                             char* __restrict__ xq) {
    size_t gid = (size_t)blockIdx.x * 256 + threadIdx.x;
    size_t base = gid * 16;
    int b = (int)(base >> 23);
    float inv = 128.0f / __uint_as_float(amax[b]);
    const float4* xs = (const float4*)(x + base);
    unsigned parts[4];
#pragma unroll
    for (int i = 0; i < 4; ++i) {
        float4 v = xs[i];
        int q0 = max(-128, min(127, (int)rintf(v.x * inv)));
        int q1 = max(-128, min(127, (int)rintf(v.y * inv)));
        int q2 = max(-128, min(127, (int)rintf(v.z * inv)));
        int q3 = max(-128, min(127, (int)rintf(v.w * inv)));
        parts[i] = (q0 & 255) | ((q1 & 255) << 8) | ((q2 & 255) << 16) | ((q3 & 255) << 24);
    }
    *(uint4*)(xq + base) = make_uint4(parts[0], parts[1], parts[2], parts[3]);
}

// ---------------- 3. int8 MFMA GEMM: A direct-to-reg, B via LDS ----------------
// BM=BN=256, BK=128 bytes. 8 waves (2M x 4N), per-wave 128x64 output.
// A-fragments load GLOBAL->REG (16 rows x 64B per wave-instr, L1/L2-hot,
// 4 waves share each wm panel) -- no LDS traffic for A. In-place register
// replacement: aF(i+1) loads issue after first MFMA half consumes aF(i)
// (WAR keeps them ordered), land ~2500 cyc before first use in iter i+1.
// B staged to LDS via global_load_lds, 2x32KiB double buffer, XOR-swizzled
// source (rule #21), one vmcnt(0)+barrier per K-tile.
// LDS traffic/tile: 32 KiB write + 64 KiB read (vs 256 KiB when A was in LDS).
__global__ __launch_bounds__(512, 2) void gemm8_kernel(
    const char* __restrict__ A, const char* __restrict__ Bt,
    const float* __restrict__ bias, const unsigned* __restrict__ amax,
    float* __restrict__ out) {
    __shared__ char sm[65536];
    const int t = threadIdx.x;
    const int l = t & 63;
    const int w = t >> 6;
    const int wm = w >> 2;
    const int wn = w & 3;
    const int rb = l & 15;
    const int sg = l >> 4;

    int bid = blockIdx.x;
    int swz = (bid & 7) * 64 + (bid >> 3);   // 512 blocks, 8 XCDs, bijective
    int mt = swz >> 4, nt = swz & 15;
    const size_t m0 = (size_t)mt * 256;
    const size_t n0 = (size_t)nt * 256;

    // B read bases (LDS): slot xor depends only on rb&7 and sg
    const int s0 = (sg ^ (rb & 7)) << 4;
    const int s1 = s0 ^ 64;
    const int baseB = (wn * 64 + rb) * 128;

    // A global base: row (m0 + wm*128 + rb), byte sg*16 within each 64B k-half
    const char* aBase = A + (m0 + wm * 128 + rb) * (size_t)K_DIM + sg * 16;

    v4i acc[8][4];
#pragma unroll
    for (int i = 0; i < 8; ++i)
#pragma unroll
        for (int j = 0; j < 4; ++j) acc[i][j] = (v4i){0, 0, 0, 0};

#define ST_B(tt)                                                             \
    if ((tt) < NT) {                                                         \
        char* lb = sm + (((tt) & 1) << 15);                                  \
        const char* gb = Bt + n0 * K_DIM + (size_t)(tt) * 128;               \
        _Pragma("unroll")                                                    \
        for (int j = 0; j < 4; ++j) {                                        \
            int p = j * 512 + t;                                             \
            int r = p >> 3, sl = p & 7;                                      \
            int s = sl ^ (r & 7);                                            \
            gload16(gb + (size_t)r * K_DIM + s * 16, lb + p * 16);           \
        }                                                                    \
    }

#define LD_A(dst, mrow, tt, ks)                                              \
    dst = *(const v4i*)(aBase + (size_t)(mrow) * (16 * K_DIM) +              \
                        (size_t)(tt) * 128 + (ks) * 64);

    v4i aF[4][2], aG[4][2], bF[4][2];

    // prologue: stage B(0); load A(0) fragments
    ST_B(0);
#pragma unroll
    for (int mi = 0; mi < 4; ++mi) {
        LD_A(aF[mi][0], mi, 0, 0); LD_A(aF[mi][1], mi, 0, 1);
        LD_A(aG[mi][0], mi + 4, 0, 0); LD_A(aG[mi][1], mi + 4, 0, 1);
    }

    for (int i = 0; i < NT; ++i) {
        const char* pb = sm + ((i & 1) << 15);
        const char* pB0 = pb + baseB + s0;
        const char* pB1 = pb + baseB + s1;
        const int nx = (i + 1 < NT) ? (i + 1) : (NT - 1);  // clamp (redundant last load)

        asm volatile("s_waitcnt vmcnt(0)" ::: "memory");
        barrier();

        // stage next B tile into the other buffer (no hazard with this tile)
        ST_B(i + 1);

        // 8 bF LDS reads: pointer + compile-time immediate
#pragma unroll
        for (int ni = 0; ni < 4; ++ni) {
            bF[ni][0] = *(const v4i*)(pB0 + ni * 2048);
            bF[ni][1] = *(const v4i*)(pB1 + ni * 2048);
        }

        __builtin_amdgcn_s_setprio(1);
        // first half: acc[0..3] uses aF(i)
#pragma unroll
        for (int mi = 0; mi < 4; ++mi)
#pragma unroll
            for (int ni = 0; ni < 4; ++ni)
#pragma unroll
                for (int ks = 0; ks < 2; ++ks)
                    acc[mi][ni] = __builtin_amdgcn_mfma_i32_16x16x64_i8(
                        aF[mi][ks], bF[ni][ks], acc[mi][ni], 0, 0, 0);
        __builtin_amdgcn_s_setprio(0);

        // prefetch aF(i+1) in-place (WAR: issues after first half consumed aF)
#pragma unroll
        for (int mi = 0; mi < 4; ++mi) {
            LD_A(aF[mi][0], mi, nx, 0); LD_A(aF[mi][1], mi, nx, 1);
        }

        __builtin_amdgcn_s_setprio(1);
        // second half: acc[4..7] uses aG(i)
#pragma unroll
        for (int mi = 0; mi < 4; ++mi)
#pragma unroll
            for (int ni = 0; ni < 4; ++ni)
#pragma unroll
                for (int ks = 0; ks < 2; ++ks)
                    acc[mi + 4][ni] = __builtin_amdgcn_mfma_i32_16x16x64_i8(
                        aG[mi][ks], bF[ni][ks], acc[mi + 4][ni], 0, 0, 0);
        __builtin_amdgcn_s_setprio(0);

        // prefetch aG(i+1) in-place
#pragma unroll
        for (int mi = 0; mi < 4; ++mi) {
            LD_A(aG[mi][0], mi + 4, nx, 0); LD_A(aG[mi][1], mi + 4, nx, 1);
        }
    }

    // ---- epilogue: dequant + bias, row-major store order ----
    float scale = __uint_as_float(amax[m0 >> 11]) * (1.0f / 128.0f) * 0.01f;
    float bv[4];
#pragma unroll
    for (int ni = 0; ni < 4; ++ni) bv[ni] = bias[n0 + wn * 64 + ni * 16 + rb];
#pragma unroll
    for (int mi = 0; mi < 8; ++mi) {
#pragma unroll
        for (int rg = 0; rg < 4; ++rg) {
            size_t row = m0 + wm * 128 + mi * 16 + sg * 4 + rg;
            float* orow = out + row * N_DIM + n0 + wn * 64 + rb;
#pragma unroll
            for (int ni = 0; ni < 4; ++ni)
                orow[ni * 16] = (float)acc[mi][ni][rg] * scale + bv[ni];
        }
    }
#undef ST_B
#undef LD_A
}

extern "C" void kernel_launch(void* const* d_in, const int* in_sizes, int n_in,
                              void* d_out, int out_size, void* d_ws, size_t ws_size,
                              hipStream_t stream) {
    const float* x = (const float*)d_in[0];
    const int* wq = (const int*)d_in[1];
    const float* bias = (const float*)d_in[2];
    float* out = (float*)d_out;

    unsigned* amax = (unsigned*)d_ws;
    char* xq = (char*)d_ws + 256;
    char* wt = (char*)d_ws + 256 + (size_t)M_DIM * K_DIM;

    hipMemsetAsync(d_ws, 0, 16, stream);

    prep1_kernel<<<dim3(8192), 256, 0, stream>>>(x, amax, wq, wt);
    quant_kernel<<<8192, 256, 0, stream>>>(x, amax, xq);
    gemm8_kernel<<<dim3(512), 512, 0, stream>>>(xq, wt, bias, amax, out);
}

// Round 6
// 230.689 us; speedup vs baseline: 1.7601x; 1.7601x over previous
//
#include <hip/hip_runtime.h>
#include <stdint.h>

#define K_DIM 4096
#define N_DIM 4096
#define M_DIM 8192   // B*S = 4*2048
#define S_ROWS 2048
#define NT 32        // K tiles of 128 bytes

typedef int v4i __attribute__((ext_vector_type(4)));

__device__ __forceinline__ void gload16(const void* g, void* l) {
    __builtin_amdgcn_global_load_lds(
        (const __attribute__((address_space(1))) unsigned int*)g,
        (__attribute__((address_space(3))) unsigned int*)l, 16, 0, 0);
}

__device__ __forceinline__ void barrier() {
    asm volatile("" ::: "memory");
    __builtin_amdgcn_s_barrier();
    asm volatile("" ::: "memory");
}

// ---------------- 1. fused prep: absmax (blocks 0..4095) + wtrans (4096..8191) ----------------
__global__ void prep1_kernel(const float* __restrict__ x, unsigned* __restrict__ amax,
                             const int* __restrict__ wq, char* __restrict__ wt) {
    __shared__ unsigned lds[64 * 17];
    if (blockIdx.x < 4096) {
        int b = blockIdx.x >> 10;
        int bx = blockIdx.x & 1023;
        const float4* xb = (const float4*)(x + (size_t)b * S_ROWS * K_DIM);
        int tid = bx * 256 + threadIdx.x;
        const int stride = 1024 * 256;
        float m = 0.f;
#pragma unroll
        for (int i = 0; i < 8; ++i) {
            float4 v = xb[tid + i * stride];
            m = fmaxf(m, fmaxf(fmaxf(fabsf(v.x), fabsf(v.y)),
                               fmaxf(fabsf(v.z), fabsf(v.w))));
        }
#pragma unroll
        for (int off = 32; off; off >>= 1)
            m = fmaxf(m, __shfl_xor(m, off));
        float* red = (float*)lds;
        if ((threadIdx.x & 63) == 0) red[threadIdx.x >> 6] = m;
        __syncthreads();
        if (threadIdx.x == 0) {
            m = fmaxf(fmaxf(red[0], red[1]), fmaxf(red[2], red[3]));
            atomicMax(&amax[b], __float_as_uint(m));
        }
    } else {
        int wb = blockIdx.x - 4096;
        int n0 = (wb & 63) * 64;
        int k0 = (wb >> 6) * 64;
        int t = threadIdx.x;
        int c = t & 63;
        int g = t >> 6;
#pragma unroll
        for (int rep = 0; rep < 4; ++rep) {
            int kb = g * 16 + rep * 4;
            int v0 = wq[(size_t)(k0 + kb + 0) * N_DIM + n0 + c];
            int v1 = wq[(size_t)(k0 + kb + 1) * N_DIM + n0 + c];
            int v2 = wq[(size_t)(k0 + kb + 2) * N_DIM + n0 + c];
            int v3 = wq[(size_t)(k0 + kb + 3) * N_DIM + n0 + c];
            lds[c * 17 + (kb >> 2)] =
                (v0 & 255) | ((v1 & 255) << 8) | ((v2 & 255) << 16) | ((v3 & 255) << 24);
        }
        __syncthreads();
        int row = t >> 2;
        int ch = t & 3;
        uint4 o;
        o.x = lds[row * 17 + ch * 4 + 0];
        o.y = lds[row * 17 + ch * 4 + 1];
        o.z = lds[row * 17 + ch * 4 + 2];
        o.w = lds[row * 17 + ch * 4 + 3];
        *(uint4*)(wt + (size_t)(n0 + row) * K_DIM + k0 + ch * 16) = o;
    }
}

// ---------------- 2. quantize x -> int8 ----------------
__global__ void quant_kernel(const float* __restrict__ x,
                             const unsigned* __restrict__ amax,
                             char* __restrict__ xq) {
    size_t gid = (size_t)blockIdx.x * 256 + threadIdx.x;
    size_t base = gid * 16;
    int b = (int)(base >> 23);
    float inv = 128.0f / __uint_as_float(amax[b]);
    const float4* xs = (const float4*)(x + base);
    unsigned parts[4];
#pragma unroll
    for (int i = 0; i < 4; ++i) {
        float4 v = xs[i];
        int q0 = max(-128, min(127, (int)rintf(v.x * inv)));
        int q1 = max(-128, min(127, (int)rintf(v.y * inv)));
        int q2 = max(-128, min(127, (int)rintf(v.z * inv)));
        int q3 = max(-128, min(127, (int)rintf(v.w * inv)));
        parts[i] = (q0 & 255) | ((q1 & 255) << 8) | ((q2 & 255) << 16) | ((q3 & 255) << 24);
    }
    *(uint4*)(xq + base) = make_uint4(parts[0], parts[1], parts[2], parts[3]);
}

// ---------------- 3. int8 MFMA GEMM, 256x256 tile, 8-wave, 1-barrier K-loop ----------------
// Round-4 structure (best measured): A and B both staged to LDS via
// global_load_lds (XOR-swizzled source, rule #21), 2x64KiB double buffer,
// one vmcnt(0)+barrier per K-tile, precomputed LDS read addresses.
// Round-6 changes:
//  (a) epilogue uses __builtin_nontemporal_store -> output stream no longer
//      evicts the 48 MB input set from L3; staging becomes L3/L2-hit.
//  (b) bid->(mt,nt) mapping gives each XCD an 8x8 tile region (co-resident
//      round = 4mt x 8nt) -> smaller per-XCD working set, better L2 reuse.
__global__ __launch_bounds__(512, 2) void gemm8_kernel(
    const char* __restrict__ A, const char* __restrict__ Bt,
    const float* __restrict__ bias, const unsigned* __restrict__ amax,
    float* __restrict__ out) {
    __shared__ char sm[131072];
    const int t = threadIdx.x;
    const int l = t & 63;
    const int w = t >> 6;
    const int wm = w >> 2;
    const int wn = w & 3;
    const int rb = l & 15;
    const int sg = l >> 4;

    // XCD-region mapping: xcd owns an 8x8 tile block of the 32x16 grid.
    int bid = blockIdx.x;
    int xcd = bid & 7;
    int idx = bid >> 3;                       // 0..63
    int mt = (xcd >> 1) * 8 + (idx >> 3);     // 0..31
    int nt = (xcd & 1) * 8 + (idx & 7);       // 0..15
    const size_t m0 = (size_t)mt * 256;
    const size_t n0 = (size_t)nt * 256;

    // precomputed read bases: slot xor depends only on rb&7 and sg
    const int s0 = (sg ^ (rb & 7)) << 4;     // ks=0 slot byte offset
    const int s1 = s0 ^ 64;                  // ks=1
    const int baseA = (wm * 128 + rb) * 128;
    const int baseB = 32768 + (wn * 64 + rb) * 128;

    v4i acc[8][4];
#pragma unroll
    for (int i = 0; i < 8; ++i)
#pragma unroll
        for (int j = 0; j < 4; ++j) acc[i][j] = (v4i){0, 0, 0, 0};

#define ST_FULL(tt)                                                          \
    if ((tt) < NT) {                                                         \
        char* lb = sm + (((tt) & 1) << 16);                                  \
        const char* ga = A + m0 * K_DIM + (size_t)(tt) * 128;                \
        const char* gb = Bt + n0 * K_DIM + (size_t)(tt) * 128;               \
        _Pragma("unroll")                                                    \
        for (int j = 0; j < 4; ++j) {                                        \
            int p = j * 512 + t;                                             \
            int r = p >> 3, sl = p & 7;                                      \
            int s = sl ^ (r & 7);                                            \
            gload16(ga + (size_t)r * K_DIM + s * 16, lb + p * 16);           \
        }                                                                    \
        _Pragma("unroll")                                                    \
        for (int j = 0; j < 4; ++j) {                                        \
            int p = j * 512 + t;                                             \
            int r = p >> 3, sl = p & 7;                                      \
            int s = sl ^ (r & 7);                                            \
            gload16(gb + (size_t)r * K_DIM + s * 16, lb + 32768 + p * 16);   \
        }                                                                    \
    }

    // prologue: stage tile 0
    ST_FULL(0);

    v4i aF[4][2], aG[4][2], bF[4][2];

    for (int i = 0; i < NT; ++i) {
        const char* pb = sm + ((i & 1) << 16);
        const char* pA0 = pb + baseA + s0;
        const char* pA1 = pb + baseA + s1;
        const char* pB0 = pb + baseB + s0;
        const char* pB1 = pb + baseB + s1;

        asm volatile("s_waitcnt vmcnt(0)" ::: "memory");
        barrier();

        // all 24 fragment reads: pointer + compile-time immediate
#pragma unroll
        for (int mi = 0; mi < 4; ++mi) {
            aF[mi][0] = *(const v4i*)(pA0 + mi * 2048);
            aF[mi][1] = *(const v4i*)(pA1 + mi * 2048);
        }
#pragma unroll
        for (int ni = 0; ni < 4; ++ni) {
            bF[ni][0] = *(const v4i*)(pB0 + ni * 2048);
            bF[ni][1] = *(const v4i*)(pB1 + ni * 2048);
        }
#pragma unroll
        for (int mi = 0; mi < 4; ++mi) {
            aG[mi][0] = *(const v4i*)(pA0 + mi * 2048 + 8192);
            aG[mi][1] = *(const v4i*)(pA1 + mi * 2048 + 8192);
        }

        // stage next tile into the other buffer (no hazard with this tile)
        ST_FULL(i + 1);

        __builtin_amdgcn_s_setprio(1);
#pragma unroll
        for (int mi = 0; mi < 4; ++mi)
#pragma unroll
            for (int ni = 0; ni < 4; ++ni)
#pragma unroll
                for (int ks = 0; ks < 2; ++ks)
                    acc[mi][ni] = __builtin_amdgcn_mfma_i32_16x16x64_i8(
                        aF[mi][ks], bF[ni][ks], acc[mi][ni], 0, 0, 0);
#pragma unroll
        for (int mi = 0; mi < 4; ++mi)
#pragma unroll
            for (int ni = 0; ni < 4; ++ni)
#pragma unroll
                for (int ks = 0; ks < 2; ++ks)
                    acc[mi + 4][ni] = __builtin_amdgcn_mfma_i32_16x16x64_i8(
                        aG[mi][ks], bF[ni][ks], acc[mi + 4][ni], 0, 0, 0);
        __builtin_amdgcn_s_setprio(0);
    }

    // ---- epilogue: dequant + bias, non-temporal stores (keep inputs in L3) ----
    float scale = __uint_as_float(amax[m0 >> 11]) * (1.0f / 128.0f) * 0.01f;
    float bv[4];
#pragma unroll
    for (int ni = 0; ni < 4; ++ni) bv[ni] = bias[n0 + wn * 64 + ni * 16 + rb];
#pragma unroll
    for (int mi = 0; mi < 8; ++mi) {
#pragma unroll
        for (int rg = 0; rg < 4; ++rg) {
            size_t row = m0 + wm * 128 + mi * 16 + sg * 4 + rg;
            float* orow = out + row * N_DIM + n0 + wn * 64 + rb;
#pragma unroll
            for (int ni = 0; ni < 4; ++ni)
                __builtin_nontemporal_store((float)acc[mi][ni][rg] * scale + bv[ni],
                                            &orow[ni * 16]);
        }
    }
#undef ST_FULL
}

extern "C" void kernel_launch(void* const* d_in, const int* in_sizes, int n_in,
                              void* d_out, int out_size, void* d_ws, size_t ws_size,
                              hipStream_t stream) {
    const float* x = (const float*)d_in[0];
    const int* wq = (const int*)d_in[1];
    const float* bias = (const float*)d_in[2];
    float* out = (float*)d_out;

    unsigned* amax = (unsigned*)d_ws;
    char* xq = (char*)d_ws + 256;
    char* wt = (char*)d_ws + 256 + (size_t)M_DIM * K_DIM;

    hipMemsetAsync(d_ws, 0, 16, stream);

    prep1_kernel<<<dim3(8192), 256, 0, stream>>>(x, amax, wq, wt);
    quant_kernel<<<8192, 256, 0, stream>>>(x, amax, xq);
    gemm8_kernel<<<dim3(512), 512, 0, stream>>>(xq, wt, bias, amax, out);
}

// Round 7
// 225.206 us; speedup vs baseline: 1.8030x; 1.0243x over previous
//
#include <hip/hip_runtime.h>
#include <stdint.h>

#define K_DIM 4096
#define N_DIM 4096
#define M_DIM 8192   // B*S = 4*2048
#define S_ROWS 2048
#define NT 32        // K tiles of 128 bytes

typedef int v4i __attribute__((ext_vector_type(4)));

__device__ __forceinline__ void gload16(const void* g, void* l) {
    __builtin_amdgcn_global_load_lds(
        (const __attribute__((address_space(1))) unsigned int*)g,
        (__attribute__((address_space(3))) unsigned int*)l, 16, 0, 0);
}

__device__ __forceinline__ void barrier() {
    asm volatile("" ::: "memory");
    __builtin_amdgcn_s_barrier();
    asm volatile("" ::: "memory");
}

// ---------------- 1. fused prep: absmax (blocks 0..4095) + wtrans (4096..8191) ----------------
__global__ void prep1_kernel(const float* __restrict__ x, unsigned* __restrict__ amax,
                             const int* __restrict__ wq, char* __restrict__ wt) {
    __shared__ unsigned lds[64 * 17];
    if (blockIdx.x < 4096) {
        int b = blockIdx.x >> 10;
        int bx = blockIdx.x & 1023;
        const float4* xb = (const float4*)(x + (size_t)b * S_ROWS * K_DIM);
        int tid = bx * 256 + threadIdx.x;
        const int stride = 1024 * 256;
        float m = 0.f;
#pragma unroll
        for (int i = 0; i < 8; ++i) {
            float4 v = xb[tid + i * stride];
            m = fmaxf(m, fmaxf(fmaxf(fabsf(v.x), fabsf(v.y)),
                               fmaxf(fabsf(v.z), fabsf(v.w))));
        }
#pragma unroll
        for (int off = 32; off; off >>= 1)
            m = fmaxf(m, __shfl_xor(m, off));
        float* red = (float*)lds;
        if ((threadIdx.x & 63) == 0) red[threadIdx.x >> 6] = m;
        __syncthreads();
        if (threadIdx.x == 0) {
            m = fmaxf(fmaxf(red[0], red[1]), fmaxf(red[2], red[3]));
            atomicMax(&amax[b], __float_as_uint(m));
        }
    } else {
        int wb = blockIdx.x - 4096;
        int n0 = (wb & 63) * 64;
        int k0 = (wb >> 6) * 64;
        int t = threadIdx.x;
        int c = t & 63;
        int g = t >> 6;
#pragma unroll
        for (int rep = 0; rep < 4; ++rep) {
            int kb = g * 16 + rep * 4;
            int v0 = wq[(size_t)(k0 + kb + 0) * N_DIM + n0 + c];
            int v1 = wq[(size_t)(k0 + kb + 1) * N_DIM + n0 + c];
            int v2 = wq[(size_t)(k0 + kb + 2) * N_DIM + n0 + c];
            int v3 = wq[(size_t)(k0 + kb + 3) * N_DIM + n0 + c];
            lds[c * 17 + (kb >> 2)] =
                (v0 & 255) | ((v1 & 255) << 8) | ((v2 & 255) << 16) | ((v3 & 255) << 24);
        }
        __syncthreads();
        int row = t >> 2;
        int ch = t & 3;
        uint4 o;
        o.x = lds[row * 17 + ch * 4 + 0];
        o.y = lds[row * 17 + ch * 4 + 1];
        o.z = lds[row * 17 + ch * 4 + 2];
        o.w = lds[row * 17 + ch * 4 + 3];
        *(uint4*)(wt + (size_t)(n0 + row) * K_DIM + k0 + ch * 16) = o;
    }
}

// ---------------- 2. quantize x -> int8 ----------------
__global__ void quant_kernel(const float* __restrict__ x,
                             const unsigned* __restrict__ amax,
                             char* __restrict__ xq) {
    size_t gid = (size_t)blockIdx.x * 256 + threadIdx.x;
    size_t base = gid * 16;
    int b = (int)(base >> 23);
    float inv = 128.0f / __uint_as_float(amax[b]);
    const float4* xs = (const float4*)(x + base);
    unsigned parts[4];
#pragma unroll
    for (int i = 0; i < 4; ++i) {
        float4 v = xs[i];
        int q0 = max(-128, min(127, (int)rintf(v.x * inv)));
        int q1 = max(-128, min(127, (int)rintf(v.y * inv)));
        int q2 = max(-128, min(127, (int)rintf(v.z * inv)));
        int q3 = max(-128, min(127, (int)rintf(v.w * inv)));
        parts[i] = (q0 & 255) | ((q1 & 255) << 8) | ((q2 & 255) << 16) | ((q3 & 255) << 24);
    }
    *(uint4*)(xq + base) = make_uint4(parts[0], parts[1], parts[2], parts[3]);
}

// ---------------- 3. int8 MFMA GEMM, 256x256 tile, 8-wave, counted-vmcnt pipeline ----------------
// R4 skeleton (best: 132us): A,B staged to LDS via global_load_lds (XOR-swizzled
// source, rule #21), 2x64KiB double buffer, precomputed LDS read addresses,
// R4 XCD swizzle, plain epilogue stores.
// R7 schedule (T4): per tile i:
//   barrier            -- all waves done reading tile i-1 (its buffer is dead)
//   ST_FULL(i+1)       -- issue 8 loads into buf[(i+1)&1], full-iteration slack
//   vmcnt(8)           -- wait MY stage(i) (8 oldest); stage(i+1) stays in flight
//   barrier            -- publish all waves' stage(i) LDS writes
//   body: ds_read groups interleaved between MFMA quartets so the LDS read
//         burst overlaps the matrix pipe.
// Last iter: no new stage -> vmcnt(0).
__global__ __launch_bounds__(512, 2) void gemm8_kernel(
    const char* __restrict__ A, const char* __restrict__ Bt,
    const float* __restrict__ bias, const unsigned* __restrict__ amax,
    float* __restrict__ out) {
    __shared__ char sm[131072];
    const int t = threadIdx.x;
    const int l = t & 63;
    const int w = t >> 6;
    const int wm = w >> 2;
    const int wn = w & 3;
    const int rb = l & 15;
    const int sg = l >> 4;

    int bid = blockIdx.x;
    int swz = (bid & 7) * 64 + (bid >> 3);   // 512 blocks, 8 XCDs, bijective
    int mt = swz >> 4, nt = swz & 15;
    const size_t m0 = (size_t)mt * 256;
    const size_t n0 = (size_t)nt * 256;

    // precomputed read bases: slot xor depends only on rb&7 and sg
    const int s0 = (sg ^ (rb & 7)) << 4;     // ks=0 slot byte offset
    const int s1 = s0 ^ 64;                  // ks=1
    const int baseA = (wm * 128 + rb) * 128;
    const int baseB = 32768 + (wn * 64 + rb) * 128;

    v4i acc[8][4];
#pragma unroll
    for (int i = 0; i < 8; ++i)
#pragma unroll
        for (int j = 0; j < 4; ++j) acc[i][j] = (v4i){0, 0, 0, 0};

#define ST_FULL(tt)                                                          \
    if ((tt) < NT) {                                                         \
        char* lb = sm + (((tt) & 1) << 16);                                  \
        const char* ga = A + m0 * K_DIM + (size_t)(tt) * 128;                \
        const char* gb = Bt + n0 * K_DIM + (size_t)(tt) * 128;               \
        _Pragma("unroll")                                                    \
        for (int j = 0; j < 4; ++j) {                                        \
            int p = j * 512 + t;                                             \
            int r = p >> 3, sl = p & 7;                                      \
            int s = sl ^ (r & 7);                                            \
            gload16(ga + (size_t)r * K_DIM + s * 16, lb + p * 16);           \
        }                                                                    \
        _Pragma("unroll")                                                    \
        for (int j = 0; j < 4; ++j) {                                        \
            int p = j * 512 + t;                                             \
            int r = p >> 3, sl = p & 7;                                      \
            int s = sl ^ (r & 7);                                            \
            gload16(gb + (size_t)r * K_DIM + s * 16, lb + 32768 + p * 16);   \
        }                                                                    \
    }

#define MFMA_PAIR(accrow, afrag)                                             \
    _Pragma("unroll")                                                        \
    for (int ni = 0; ni < 4; ++ni)                                           \
        _Pragma("unroll")                                                    \
        for (int ks = 0; ks < 2; ++ks)                                       \
            acc[accrow][ni] = __builtin_amdgcn_mfma_i32_16x16x64_i8(         \
                afrag[ks], bF[ni][ks], acc[accrow][ni], 0, 0, 0);

    // prologue: stage tile 0
    ST_FULL(0);

    v4i aP[2][2], bF[4][2];

    for (int i = 0; i < NT; ++i) {
        const char* pb = sm + ((i & 1) << 16);
        const char* pA0 = pb + baseA + s0;
        const char* pA1 = pb + baseA + s1;
        const char* pB0 = pb + baseB + s0;
        const char* pB1 = pb + baseB + s1;

        barrier();                 // all waves finished reading tile i-1
        ST_FULL(i + 1);            // overwrite dead buffer; full-iter slack
        if (i == NT - 1) { asm volatile("s_waitcnt vmcnt(0)" ::: "memory"); }
        else             { asm volatile("s_waitcnt vmcnt(8)" ::: "memory"); }
        barrier();                 // tile i fully published in LDS

        // B fragments (shared by all MFMA groups)
#pragma unroll
        for (int ni = 0; ni < 4; ++ni) {
            bF[ni][0] = *(const v4i*)(pB0 + ni * 2048);
            bF[ni][1] = *(const v4i*)(pB1 + ni * 2048);
        }
        // interleave: A reads for group g+1 issue while group g's MFMAs run
        aP[0][0] = *(const v4i*)(pA0 + 0 * 2048); aP[0][1] = *(const v4i*)(pA1 + 0 * 2048);
        aP[1][0] = *(const v4i*)(pA0 + 1 * 2048); aP[1][1] = *(const v4i*)(pA1 + 1 * 2048);
        __builtin_amdgcn_s_setprio(1);
        MFMA_PAIR(0, aP[0]); MFMA_PAIR(1, aP[1]);
        aP[0][0] = *(const v4i*)(pA0 + 2 * 2048); aP[0][1] = *(const v4i*)(pA1 + 2 * 2048);
        aP[1][0] = *(const v4i*)(pA0 + 3 * 2048); aP[1][1] = *(const v4i*)(pA1 + 3 * 2048);
        MFMA_PAIR(2, aP[0]); MFMA_PAIR(3, aP[1]);
        aP[0][0] = *(const v4i*)(pA0 + 0 * 2048 + 8192); aP[0][1] = *(const v4i*)(pA1 + 0 * 2048 + 8192);
        aP[1][0] = *(const v4i*)(pA0 + 1 * 2048 + 8192); aP[1][1] = *(const v4i*)(pA1 + 1 * 2048 + 8192);
        MFMA_PAIR(4, aP[0]); MFMA_PAIR(5, aP[1]);
        aP[0][0] = *(const v4i*)(pA0 + 2 * 2048 + 8192); aP[0][1] = *(const v4i*)(pA1 + 2 * 2048 + 8192);
        aP[1][0] = *(const v4i*)(pA0 + 3 * 2048 + 8192); aP[1][1] = *(const v4i*)(pA1 + 3 * 2048 + 8192);
        MFMA_PAIR(6, aP[0]); MFMA_PAIR(7, aP[1]);
        __builtin_amdgcn_s_setprio(0);
    }

    // ---- epilogue: dequant + bias, row-major store order (stores merge in L2) ----
    float scale = __uint_as_float(amax[m0 >> 11]) * (1.0f / 128.0f) * 0.01f;
    float bv[4];
#pragma unroll
    for (int ni = 0; ni < 4; ++ni) bv[ni] = bias[n0 + wn * 64 + ni * 16 + rb];
#pragma unroll
    for (int mi = 0; mi < 8; ++mi) {
#pragma unroll
        for (int rg = 0; rg < 4; ++rg) {
            size_t row = m0 + wm * 128 + mi * 16 + sg * 4 + rg;
            float* orow = out + row * N_DIM + n0 + wn * 64 + rb;
#pragma unroll
            for (int ni = 0; ni < 4; ++ni)
                orow[ni * 16] = (float)acc[mi][ni][rg] * scale + bv[ni];
        }
    }
#undef ST_FULL
#undef MFMA_PAIR
}

extern "C" void kernel_launch(void* const* d_in, const int* in_sizes, int n_in,
                              void* d_out, int out_size, void* d_ws, size_t ws_size,
                              hipStream_t stream) {
    const float* x = (const float*)d_in[0];
    const int* wq = (const int*)d_in[1];
    const float* bias = (const float*)d_in[2];
    float* out = (float*)d_out;

    unsigned* amax = (unsigned*)d_ws;
    char* xq = (char*)d_ws + 256;
    char* wt = (char*)d_ws + 256 + (size_t)M_DIM * K_DIM;

    hipMemsetAsync(d_ws, 0, 16, stream);

    prep1_kernel<<<dim3(8192), 256, 0, stream>>>(x, amax, wq, wt);
    quant_kernel<<<8192, 256, 0, stream>>>(x, amax, xq);
    gemm8_kernel<<<dim3(512), 512, 0, stream>>>(xq, wt, bias, amax, out);
}